// Round 4
// baseline (602.567 us; speedup 1.0000x reference)
//
#include <hip/hip_runtime.h>

// Depthwise 7x7 cross-correlation, same padding.
// x:    [8, 256, 64, 64]   fp32
// tmpl: [8, 8, 256, 7, 7]  fp32  (nt, bs, nc, ht, wt)
// out:  [8, 8, 256, 64, 64] fp32
//
// One block per (b,c) plane; x staged into LDS once, reused by all 8 templates.
// Structure: 8x4 per-thread output tile, 2 templates concurrently (half-block
// each, wave-uniform t via readfirstlane), 4 rounds.
//
// v5 key change: the 49 taps are wave-uniform -> force them into SGPRs
// (readfirstlane on bits loaded from a uniform global address). SGPRs don't
// count against the VGPR occupancy budget, and v_fmac_f32 takes one SGPR
// operand. This drops VGPR demand from ~150-190 (v4, -> 2 waves/SIMD) to
// ~75-95, so __launch_bounds__(256,2) (empirical cap = 128) is now SAFE
// (v3's spill was the 49 unspillable tap VGPRs; the only long-lived VGPRs
// left are the 32 acc) and pins 4 waves/SIMD.
// Also: zero only the 944 pad cells (disjoint from interior) -> single
// __syncthreads(); tpl LDS array + staging loop deleted.
// History: (256,4)=cap64 huge spill 1365us; (256,2)=cap128 part spill 441us;
// uncapped = no spill but 2 waves/SIMD, net == v1 (~360us bench).
// Bank conflicts measured ~1% of cycles at LSTR=72: even 8-lane/16B-slot
// distribution is the ds_read_b128 minimum; no swizzle needed.

#define NT 8
#define BS 8
#define NC 256
#define HW 64
#define PLANE (HW * HW)          // 4096
#define LROWS 70
#define LSTR  72                 // row stride in floats; 288 B (16B mult)

__global__ __launch_bounds__(256, 2) void dwxcorr_kernel(
    const float* __restrict__ x,
    const float* __restrict__ tm,
    float* __restrict__ out)
{
    __shared__ __align__(16) float xpl[LROWS * LSTR];     // 20160 B

    const int bc  = blockIdx.x;          // b*256 + c, 0..2047
    const int tid = threadIdx.x;

    // ---- zero ONLY the pad cells: 236 float4 total, <=1 per thread ----
    // rows 0..2 full (54 f4), rows 67..69 full (54 f4),
    // rows 3..66 cols 0..3 (64 f4), rows 3..66 cols 68..71 (64 f4).
    if (tid < 236) {
        int off;
        if (tid < 54)       off = tid * 4;                        // rows 0..2
        else if (tid < 108) off = 67 * LSTR + (tid - 54) * 4;     // rows 67..69
        else if (tid < 172) off = (3 + (tid - 108)) * LSTR;       // left pad
        else                off = (3 + (tid - 172)) * LSTR + 68;  // right pad
        *(float4*)&xpl[off] = make_float4(0.f, 0.f, 0.f, 0.f);
    }

    // ---- stage x interior: 1024 float4 loads, coalesced (disjoint from pads)
    const float* xp = x + bc * PLANE;
    for (int i = tid; i < PLANE / 4; i += 256) {
        float4 v = ((const float4*)xp)[i];
        int row = i >> 4;              // 16 float4 per 64-wide row
        int c4  = (i & 15) << 2;
        *(float4*)&xpl[(row + 3) * LSTR + 4 + c4] = v;
    }
    __syncthreads();

    // ---- compute geometry: 128 threads cover the plane per template ----
    // half 0 (waves 0-1) does template 2*rnd+0, half 1 (waves 2-3) 2*rnd+1.
    // tid>>7 is wave-uniform; readfirstlane makes the compiler see it.
    const int half = __builtin_amdgcn_readfirstlane(tid >> 7);
    const int lid  = tid & 127;
    const int tx   = lid & 15;           // col group: cols 4*tx..4*tx+3
    const int ty   = lid >> 4;           // row group: rows 8*ty..8*ty+7
    const int col0 = tx << 2;
    const int row0 = ty << 3;

    for (int rnd = 0; rnd < 4; ++rnd) {
        const int t = (rnd << 1) + half;

        // ---- taps -> SGPRs: uniform global address, readfirstlane the bits.
        // tm layout: t*(8*256*49) + (b*256+c)*49 + k
        const float* wg = tm + ((size_t)t * (BS * NC) + bc) * 49;
        float w[49];
        #pragma unroll
        for (int k = 0; k < 49; ++k) {
            union { float f; int i; } u;
            u.f = wg[k];
            u.i = __builtin_amdgcn_readfirstlane(u.i);
            w[k] = u.f;
        }

        float acc[8][4];
        #pragma unroll
        for (int r = 0; r < 8; ++r)
            #pragma unroll
            for (int j = 0; j < 4; ++j) acc[r][j] = 0.0f;

        // input rows for output rows row0..row0+7: LDS rows row0..row0+13
        #pragma unroll
        for (int ir = 0; ir < 14; ++ir) {
            const float* rowp = &xpl[(row0 + ir) * LSTR + col0];
            float xw[12];
            float4 a = *(const float4*)(rowp);
            float4 b = *(const float4*)(rowp + 4);
            float4 c = *(const float4*)(rowp + 8);
            xw[0] = a.x; xw[1]  = a.y; xw[2]  = a.z; xw[3]  = a.w;
            xw[4] = b.x; xw[5]  = b.y; xw[6]  = b.z; xw[7]  = b.w;
            xw[8] = c.x; xw[9]  = c.y; xw[10] = c.z; xw[11] = c.w;

            #pragma unroll
            for (int r = 0; r < 8; ++r) {
                const int ky = ir - r;            // compile-time after unroll
                if (ky >= 0 && ky < 7) {
                    #pragma unroll
                    for (int kx = 0; kx < 7; ++kx) {
                        const float tv = w[ky * 7 + kx];   // SGPR operand
                        #pragma unroll
                        for (int j = 0; j < 4; ++j)
                            acc[r][j] = fmaf(xw[j + kx + 1], tv, acc[r][j]);
                    }
                }
            }
        }

        // ---- store 8 rows x float4, coalesced across tx (256B runs) ----
        float* op = out + (size_t)(t * (BS * NC) + bc) * PLANE + row0 * HW + col0;
        #pragma unroll
        for (int r = 0; r < 8; ++r) {
            float4 v = make_float4(acc[r][0], acc[r][1], acc[r][2], acc[r][3]);
            *(float4*)(op + r * HW) = v;
        }
    }
}

extern "C" void kernel_launch(void* const* d_in, const int* in_sizes, int n_in,
                              void* d_out, int out_size, void* d_ws, size_t ws_size,
                              hipStream_t stream) {
    const float* x  = (const float*)d_in[0];
    const float* tm = (const float*)d_in[1];
    float* out = (float*)d_out;
    dwxcorr_kernel<<<BS * NC, 256, 0, stream>>>(x, tm, out);
}

// Round 5
// 322.199 us; speedup vs baseline: 1.8702x; 1.8702x over previous
//
#include <hip/hip_runtime.h>

// Depthwise 7x7 cross-correlation, same padding.
// x:    [8, 256, 64, 64]   fp32
// tmpl: [8, 8, 256, 7, 7]  fp32  (nt, bs, nc, ht, wt)
// out:  [8, 8, 256, 64, 64] fp32
//
// One block per (b,c) plane; x staged into LDS once, reused by all 8 templates.
// Structure: 8x4 per-thread output tile, 2 templates concurrently (half-block
// each, wave-uniform t), 4 rounds; 49 taps forced into SGPRs via readfirstlane
// (v5: SGPR_Count 96->112 confirmed it works; SGPRs are free for occupancy).
//
// v6 key change: bound the ds_read hoisting. With the 14-row loop fully
// unrolled the scheduler hoists up to 42 ds_read_b128 windows -> 168 VGPRs of
// in-flight data; that (not the taps) is what pegged every cap and spilled
// (v3: cap128 0.9GB scratch 441us; v5: cap128+SGPR taps, still 0.55GB scratch
// 385us; v4 uncapped: no spill but ~160 VGPR -> 2 waves/SIMD, 155us).
// sched_barrier(0) every 2 ir-iterations caps the motion window at <=6 reads
// (+24 VGPR): live set ~= acc 32 + 2 windows 24 + addr 20 ~= 80-90.
// NO VGPR cap: if fences work, allocator lands <=128 -> 4 waves/SIMD
// naturally; if not, worst case is v4 (2 waves), never the spill cliff.
// Each fence region holds ~200+ FMA cycles vs 3 LDS reads, so order-pinning
// cost is negligible (unlike the m141 load-critical case).
// Bank conflicts measured ~1% at LSTR=72 (even 8-lane/16B-slot distribution,
// the ds_read_b128 minimum) -- no swizzle needed.

#define NT 8
#define BS 8
#define NC 256
#define HW 64
#define PLANE (HW * HW)          // 4096
#define LROWS 70
#define LSTR  72                 // row stride in floats; 288 B (16B mult)

__global__ __launch_bounds__(256) void dwxcorr_kernel(
    const float* __restrict__ x,
    const float* __restrict__ tm,
    float* __restrict__ out)
{
    __shared__ __align__(16) float xpl[LROWS * LSTR];     // 20160 B

    const int bc  = blockIdx.x;          // b*256 + c, 0..2047
    const int tid = threadIdx.x;

    // ---- zero ONLY the pad cells: 236 float4 total, <=1 per thread ----
    // rows 0..2 full (54 f4), rows 67..69 full (54 f4),
    // rows 3..66 cols 0..3 (64 f4), rows 3..66 cols 68..71 (64 f4).
    if (tid < 236) {
        int off;
        if (tid < 54)       off = tid * 4;                        // rows 0..2
        else if (tid < 108) off = 67 * LSTR + (tid - 54) * 4;     // rows 67..69
        else if (tid < 172) off = (3 + (tid - 108)) * LSTR;       // left pad
        else                off = (3 + (tid - 172)) * LSTR + 68;  // right pad
        *(float4*)&xpl[off] = make_float4(0.f, 0.f, 0.f, 0.f);
    }

    // ---- stage x interior: 1024 float4 loads, coalesced (disjoint from pads)
    const float* xp = x + bc * PLANE;
    for (int i = tid; i < PLANE / 4; i += 256) {
        float4 v = ((const float4*)xp)[i];
        int row = i >> 4;              // 16 float4 per 64-wide row
        int c4  = (i & 15) << 2;
        *(float4*)&xpl[(row + 3) * LSTR + 4 + c4] = v;
    }
    __syncthreads();

    // ---- compute geometry: 128 threads cover the plane per template ----
    // half 0 (waves 0-1) does template 2*rnd+0, half 1 (waves 2-3) 2*rnd+1.
    const int half = __builtin_amdgcn_readfirstlane(tid >> 7);
    const int lid  = tid & 127;
    const int tx   = lid & 15;           // col group: cols 4*tx..4*tx+3
    const int ty   = lid >> 4;           // row group: rows 8*ty..8*ty+7
    const int col0 = tx << 2;
    const int row0 = ty << 3;

    for (int rnd = 0; rnd < 4; ++rnd) {
        const int t = (rnd << 1) + half;

        // ---- taps -> SGPRs: uniform global address, readfirstlane the bits.
        // tm layout: t*(8*256*49) + (b*256+c)*49 + k
        const float* wg = tm + ((size_t)t * (BS * NC) + bc) * 49;
        float w[49];
        #pragma unroll
        for (int k = 0; k < 49; ++k) {
            union { float f; int i; } u;
            u.f = wg[k];
            u.i = __builtin_amdgcn_readfirstlane(u.i);
            w[k] = u.f;
        }
        // keep the tap-load burst out of the compute live range
        __builtin_amdgcn_sched_barrier(0);

        float acc[8][4];
        #pragma unroll
        for (int r = 0; r < 8; ++r)
            #pragma unroll
            for (int j = 0; j < 4; ++j) acc[r][j] = 0.0f;

        // input rows for output rows row0..row0+7: LDS rows row0..row0+13
        #pragma unroll
        for (int ir = 0; ir < 14; ++ir) {
            const float* rowp = &xpl[(row0 + ir) * LSTR + col0];
            float xw[12];
            float4 a = *(const float4*)(rowp);
            float4 b = *(const float4*)(rowp + 4);
            float4 c = *(const float4*)(rowp + 8);
            xw[0] = a.x; xw[1]  = a.y; xw[2]  = a.z; xw[3]  = a.w;
            xw[4] = b.x; xw[5]  = b.y; xw[6]  = b.z; xw[7]  = b.w;
            xw[8] = c.x; xw[9]  = c.y; xw[10] = c.z; xw[11] = c.w;

            #pragma unroll
            for (int r = 0; r < 8; ++r) {
                const int ky = ir - r;            // compile-time after unroll
                if (ky >= 0 && ky < 7) {
                    #pragma unroll
                    for (int kx = 0; kx < 7; ++kx) {
                        const float tv = w[ky * 7 + kx];   // SGPR operand
                        #pragma unroll
                        for (int j = 0; j < 4; ++j)
                            acc[r][j] = fmaf(xw[j + kx + 1], tv, acc[r][j]);
                    }
                }
            }

            // fence every 2 rows: caps ds_read hoisting window (<=6 reads in
            // flight) so the live set stays ~80-90 VGPRs. ir is unroll-const.
            if (ir & 1) __builtin_amdgcn_sched_barrier(0);
        }

        // ---- store 8 rows x float4, coalesced across tx (256B runs) ----
        float* op = out + (size_t)(t * (BS * NC) + bc) * PLANE + row0 * HW + col0;
        #pragma unroll
        for (int r = 0; r < 8; ++r) {
            float4 v = make_float4(acc[r][0], acc[r][1], acc[r][2], acc[r][3]);
            *(float4*)(op + r * HW) = v;
        }
    }
}

extern "C" void kernel_launch(void* const* d_in, const int* in_sizes, int n_in,
                              void* d_out, int out_size, void* d_ws, size_t ws_size,
                              hipStream_t stream) {
    const float* x  = (const float*)d_in[0];
    const float* tm = (const float*)d_in[1];
    float* out = (float*)d_out;
    dwxcorr_kernel<<<BS * NC, 256, 0, stream>>>(x, tm, out);
}